// Round 12
// baseline (300.570 us; speedup 1.0000x reference)
//
#include <hip/hip_runtime.h>
#include <hip/hip_bf16.h>

typedef __attribute__((ext_vector_type(4)))  int   i32x4;
typedef __attribute__((ext_vector_type(16))) int   i32x16;
typedef __attribute__((ext_vector_type(16))) float f32x16;
typedef __attribute__((ext_vector_type(8)))  short short8;

#define SC1 (1.0f/4096.0f)     // xh*wh scale: (1/16)*(1/256)
#define SC2 (1.0f/524288.0f)   // cross terms: (1/16)*(1/32768) == (1/2048)*(1/256)

static __device__ __forceinline__ float ftanh(float x) {
  float e = __builtin_amdgcn_exp2f(x * 2.885390081777927f);
  return 1.0f - 2.0f * __builtin_amdgcn_rcpf(e + 1.0f);
}
static __device__ __forceinline__ unsigned short bf16_rn(float f) {
  unsigned u = __float_as_uint(f);
  u += 0x7FFFu + ((u >> 16) & 1u);
  return (unsigned short)(u >> 16);
}
// x ~= hi/sc + lo/(sc*losc); rne via magic-add. Proven round 6.
static __device__ __forceinline__ void quant2(float x, float sc, float inv, float losc,
                                              int& hi, int& lo) {
  float t  = __builtin_fmaf(x, sc, 12582912.0f);
  hi = __float_as_int(t) - 0x4B400000;
  float hf = t - 12582912.0f;
  float r  = __builtin_fmaf(hf, -inv, x);
  float t2 = __builtin_fmaf(r, losc, 12582912.0f);
  lo = __float_as_int(t2) - 0x4B400000;
}
static __device__ __forceinline__ void gll16(const void* g, void* l) {
  __builtin_amdgcn_global_load_lds((const __attribute__((address_space(1))) unsigned int*)g,
                                   (__attribute__((address_space(3))) unsigned int*)l, 16, 0, 0);
}
#define MFMA_I8(ACC, A, B) \
  asm("v_mfma_i32_32x32x32_i8 %0, %1, %2, %0" : "+v"(ACC) : "v"(A), "v"(B))

// ---------------------------------------------------------------------------
// prep_w (verbatim round 6): pack W into chunked global_load_lds-ready streams.
// B1 per chunk kc (64KB): [Q-hi 16KB][Q-lo 16KB][V-bf16 32KB]
//   Q: byte = kc*65536 + sel*16384 + (nt*64+lane)*16 + j
//      value W[col = nt*32+(lane&31)][k = kc*32+(lane>>5)*16+j]
//   V: byte = kc*65536 + 32768 + ((nt*2+ks)*64+lane)*16 + j*2 (8 bf16)
// B2 per chunk (32KB): [K-hi 16KB][K-lo 16KB], same scheme.
// ---------------------------------------------------------------------------
__global__ void prep_w(const float* __restrict__ Wq, const float* __restrict__ Wk,
                       const float* __restrict__ Wv,
                       char* __restrict__ B1, char* __restrict__ B2) {
  int gid = blockIdx.x * 256 + threadIdx.x;   // 0..98303
  if (gid < 65536) {
    int chunk = gid >> 12, g = gid & 4095;
    char* dst = B1 + chunk * 65536 + g * 16;
    if (g < 2048) {
      int sel = g >> 10;
      int gg = g & 1023, nt = gg >> 6, lane = gg & 63;
      const float* src = Wq + (size_t)(nt * 32 + (lane & 31)) * 512 + chunk * 32 + (lane >> 5) * 16;
      union { char b[16]; i32x4 v; } ob;
#pragma unroll
      for (int j = 0; j < 16; ++j) {
        int h, l; quant2(src[j], 256.f, 1.f / 256.f, 32768.f, h, l);
        ob.b[j] = (char)(sel ? l : h);
      }
      *(i32x4*)dst = ob.v;
    } else {
      int gg = g - 2048, nt = gg >> 7, ks = (gg >> 6) & 1, lane = gg & 63;
      const float* src = Wv + (size_t)(nt * 32 + (lane & 31)) * 512 + chunk * 32 + ks * 16 + (lane >> 5) * 8;
      union { unsigned short s[8]; i32x4 v; } ob;
#pragma unroll
      for (int j = 0; j < 8; ++j) ob.s[j] = bf16_rn(src[j]);
      *(i32x4*)dst = ob.v;
    }
  } else {
    int gid2 = gid - 65536;
    int chunk = gid2 >> 11, g = gid2 & 2047;
    char* dst = B2 + chunk * 32768 + g * 16;
    int sel = g >> 10, gg = g & 1023, nt = gg >> 6, lane = gg & 63;
    const float* src = Wk + (size_t)(nt * 32 + (lane & 31)) * 512 + chunk * 32 + (lane >> 5) * 16;
    union { char b[16]; i32x4 v; } ob;
#pragma unroll
    for (int j = 0; j < 16; ++j) {
      int h, l; quant2(src[j], 256.f, 1.f / 256.f, 32768.f, h, l);
      ob.b[j] = (char)(sel ? l : h);
    }
    *(i32x4*)dst = ob.v;
  }
}

// ---- A-staging helpers: write 4 floats of x at (row, d0) of a 64x32 chunk.
// Byte layouts are verbatim round 6; only the thread->(row,d0) partition
// changed (256 threads: row = tid>>2, d0 = (tid&3)*8 and +4). ----
static __device__ __forceinline__ void stA8(char* Ab, int row, int d0, float4 xv) {
  const int mt = row >> 5, l31 = row & 31;
  int h0, l0, h1, l1, h2, l2, h3, l3;
  quant2(xv.x, 16.f, 0.0625f, 2048.f, h0, l0);
  quant2(xv.y, 16.f, 0.0625f, 2048.f, h1, l1);
  quant2(xv.z, 16.f, 0.0625f, 2048.f, h2, l2);
  quant2(xv.w, 16.f, 0.0625f, 2048.f, h3, l3);
  unsigned wh = (h0 & 255) | ((h1 & 255) << 8) | ((h2 & 255) << 16) | ((unsigned)(h3 & 255) << 24);
  unsigned wl = (l0 & 255) | ((l1 & 255) << 8) | ((l2 & 255) << 16) | ((unsigned)(l3 & 255) << 24);
  const int lane8 = (d0 >> 4) * 32 + l31, j = d0 & 15;
  *(unsigned*)(Ab + (mt * 64 + lane8) * 16 + j) = wh;          // A-hi at +0 (2KB)
  *(unsigned*)(Ab + 2048 + (mt * 64 + lane8) * 16 + j) = wl;   // A-lo at +2KB
}
static __device__ __forceinline__ void stAv(char* Ab, int row, int d0, float4 xv) {
  const int mt = row >> 5, l31 = row & 31;
  unsigned long long b0 = bf16_rn(xv.x), b1 = bf16_rn(xv.y), b2 = bf16_rn(xv.z), b3 = bf16_rn(xv.w);
  unsigned long long vv = b0 | (b1 << 16) | (b2 << 32) | (b3 << 48);
  const int ks = d0 >> 4, rem = d0 & 15, hs8 = rem >> 3, j8 = rem & 7;
  *(unsigned long long*)(Ab + ((mt * 2 + ks) * 64 + hs8 * 32 + l31) * 16 + j8 * 2) = vv;
}

// ---------------------------------------------------------------------------
// pass_q: Q path (i8 2-term, colsum). Block = 64 rows x 128 cols, 256 thr =
// 4 waves, wave w owns cols [cg*128 + w*32, +32). acc 64 regs/wave ->
// 3 waves/SIMD -> 3 blocks/CU. R6 double-buffered skeleton, offsets shifted.
// ---------------------------------------------------------------------------
__global__ __launch_bounds__(256, 3) void pass_q(
    const float* __restrict__ x, const char* __restrict__ B1,
    const float* __restrict__ bq, float* __restrict__ qpart) {
  extern __shared__ char smem[];
  char* Bb0 = smem;           char* Bb1 = smem + 8192;    // B dbuf 2x8KB
  char* Ab0 = smem + 16384;   char* Ab1 = smem + 20480;   // A dbuf 2x4KB

  const int tid = threadIdx.x, lane = tid & 63, w = tid >> 6;   // w 0..3
  const int l31 = lane & 31;
  const int tile = blockIdx.x & 1023, cg = blockIdx.x >> 10;
  const int row = tid >> 2, d0 = (tid & 3) * 8;
  const float* gxr = x + ((size_t)tile * 64 + row) * 512 + d0;

  i32x16 q1[2] = {}, q2[2] = {};

  // prologue: chunk 0 staged; chunk 1 in regs
  float4 xa = *(const float4*)(gxr);
  float4 xb = *(const float4*)(gxr + 4);
  stA8(Ab0, row, d0, xa); stA8(Ab0, row, d0 + 4, xb);
  {
    const char* src = B1 + cg * 4096 + tid * 16;
    gll16(src, Bb0 + tid * 16);                    // Q-hi slice (4KB)
    gll16(src + 16384, Bb0 + 4096 + tid * 16);     // Q-lo slice (4KB)
  }
  xa = *(const float4*)(gxr + 32);
  xb = *(const float4*)(gxr + 36);

#pragma unroll 1
  for (int c = 0; c < 16; ++c) {
    const int p = c & 1;
    char* Bc = p ? Bb1 : Bb0;  char* Bn = p ? Bb0 : Bb1;
    char* Ac = p ? Ab1 : Ab0;  char* An = p ? Ab0 : Ab1;
    __syncthreads();
    if (c < 15) {
      const char* src = B1 + (size_t)(c + 1) * 65536 + cg * 4096 + tid * 16;
      gll16(src, Bn + tid * 16);
      gll16(src + 16384, Bn + 4096 + tid * 16);
    }
    float4 xna = xa, xnb = xb;
    if (c < 14) {
      xna = *(const float4*)(gxr + (c + 2) * 32);
      xnb = *(const float4*)(gxr + (c + 2) * 32 + 4);
    }
    if (c < 15) { stA8(An, row, d0, xa); stA8(An, row, d0 + 4, xb); }

    const int lo16 = lane * 16;
    i32x4 ah0 = *(const i32x4*)(Ac + lo16);
    i32x4 ah1 = *(const i32x4*)(Ac + 1024 + lo16);
    i32x4 al0 = *(const i32x4*)(Ac + 2048 + lo16);
    i32x4 al1 = *(const i32x4*)(Ac + 3072 + lo16);
    i32x4 bh = *(const i32x4*)(Bc + w * 1024 + lo16);
    i32x4 bl = *(const i32x4*)(Bc + 4096 + w * 1024 + lo16);
    MFMA_I8(q1[0], ah0, bh);
    MFMA_I8(q2[0], ah0, bl);
    MFMA_I8(q2[0], al0, bh);
    MFMA_I8(q1[1], ah1, bh);
    MFMA_I8(q2[1], ah1, bl);
    MFMA_I8(q2[1], al1, bh);
    xa = xna; xb = xnb;
  }

  // epilogue: colsum; cols private per wave
  const int col = cg * 128 + w * 32 + l31;
  const float bc = bq[col];
  float cs = 0.f;
#pragma unroll
  for (int mt = 0; mt < 2; ++mt)
#pragma unroll
    for (int r = 0; r < 16; ++r)
      cs += ftanh(__builtin_fmaf((float)q1[mt][r], SC1,
                  __builtin_fmaf((float)q2[mt][r], SC2, bc)));
  cs += __shfl_xor(cs, 32);
  if (lane < 32) qpart[(size_t)tile * 512 + col] = cs;
}

// ---------------------------------------------------------------------------
// pass_v: V path (bf16 1-term, rowsum). Same geometry; acc 32 regs ->
// 4 waves/SIMD -> 4 blocks/CU. Partial rowsums to vpart plane [cg].
// ---------------------------------------------------------------------------
__global__ __launch_bounds__(256, 4) void pass_v(
    const float* __restrict__ x, const char* __restrict__ B1,
    const float* __restrict__ bv, float* __restrict__ vpart) {
  extern __shared__ char smem[];
  char* Bb0 = smem;           char* Bb1 = smem + 8192;    // B dbuf 2x8KB
  char* Ab0 = smem + 16384;   char* Ab1 = smem + 20480;   // A dbuf 2x4KB
  float* redv = (float*)(smem + 24576);                   // [4][64] = 1KB

  const int tid = threadIdx.x, lane = tid & 63, w = tid >> 6;
  const int l31 = lane & 31, hs = lane >> 5;
  const int tile = blockIdx.x & 1023, cg = blockIdx.x >> 10;
  const int row = tid >> 2, d0 = (tid & 3) * 8;
  const float* gxr = x + ((size_t)tile * 64 + row) * 512 + d0;

  f32x16 accv[2] = {};

  float4 xa = *(const float4*)(gxr);
  float4 xb = *(const float4*)(gxr + 4);
  stAv(Ab0, row, d0, xa); stAv(Ab0, row, d0 + 4, xb);
  {
    const char* src = B1 + 32768 + cg * 8192 + tid * 16;
    gll16(src, Bb0 + tid * 16);                 // V slice first 4KB
    gll16(src + 4096, Bb0 + 4096 + tid * 16);   // V slice second 4KB
  }
  xa = *(const float4*)(gxr + 32);
  xb = *(const float4*)(gxr + 36);

#pragma unroll 1
  for (int c = 0; c < 16; ++c) {
    const int p = c & 1;
    char* Bc = p ? Bb1 : Bb0;  char* Bn = p ? Bb0 : Bb1;
    char* Ac = p ? Ab1 : Ab0;  char* An = p ? Ab0 : Ab1;
    __syncthreads();
    if (c < 15) {
      const char* src = B1 + (size_t)(c + 1) * 65536 + 32768 + cg * 8192 + tid * 16;
      gll16(src, Bn + tid * 16);
      gll16(src + 4096, Bn + 4096 + tid * 16);
    }
    float4 xna = xa, xnb = xb;
    if (c < 14) {
      xna = *(const float4*)(gxr + (c + 2) * 32);
      xnb = *(const float4*)(gxr + (c + 2) * 32 + 4);
    }
    if (c < 15) { stAv(An, row, d0, xa); stAv(An, row, d0 + 4, xb); }

    const int lo16 = lane * 16;
#pragma unroll
    for (int ks = 0; ks < 2; ++ks) {
      short8 av0 = *(const short8*)(Ac + (0 * 2 + ks) * 1024 + lo16);
      short8 av1 = *(const short8*)(Ac + (1 * 2 + ks) * 1024 + lo16);
      short8 bvf = *(const short8*)(Bc + (w * 2 + ks) * 1024 + lo16);
      accv[0] = __builtin_amdgcn_mfma_f32_32x32x16_bf16(av0, bvf, accv[0], 0, 0, 0);
      accv[1] = __builtin_amdgcn_mfma_f32_32x32x16_bf16(av1, bvf, accv[1], 0, 0, 0);
    }
    xa = xna; xb = xnb;
  }

  // epilogue: partial rowsum over this wave's 32 cols, fold 4 waves
  const float bvc = bv[cg * 128 + w * 32 + l31];
  __syncthreads();
#pragma unroll
  for (int mt = 0; mt < 2; ++mt)
#pragma unroll
    for (int r = 0; r < 16; ++r) {
      float s = ftanh(accv[mt][r] + bvc);
#pragma unroll
      for (int off = 1; off <= 16; off <<= 1) s += __shfl_xor(s, off);
      if (l31 == 0) redv[w * 64 + mt * 32 + (r & 3) + 8 * (r >> 2) + 4 * hs] = s;
    }
  __syncthreads();
  if (tid < 64) {
    float s = redv[tid] + redv[64 + tid] + redv[128 + tid] + redv[192 + tid];
    vpart[(size_t)cg * 65536 + (size_t)tile * 64 + tid] = s;
  }
}

// ---------------------------------------------------------------------------
// pass_k: K path (i8 2-term, rowsum * q_sum). Same geometry as pass_q.
// Partial rowsums to spart plane [cg].
// ---------------------------------------------------------------------------
__global__ __launch_bounds__(256, 3) void pass_k(
    const float* __restrict__ x, const char* __restrict__ B2,
    const float* __restrict__ bk, const float* __restrict__ q_sum,
    float* __restrict__ spart) {
  extern __shared__ char smem[];
  char* Bb0 = smem;           char* Bb1 = smem + 8192;
  char* Ab0 = smem + 16384;   char* Ab1 = smem + 20480;
  float* redk = (float*)(smem + 24576);                   // [4][64]

  const int tid = threadIdx.x, lane = tid & 63, w = tid >> 6;
  const int l31 = lane & 31, hs = lane >> 5;
  const int tile = blockIdx.x & 1023, cg = blockIdx.x >> 10;
  const int row = tid >> 2, d0 = (tid & 3) * 8;
  const float* gxr = x + ((size_t)tile * 64 + row) * 512 + d0;

  i32x16 k1[2] = {}, k2[2] = {};

  float4 xa = *(const float4*)(gxr);
  float4 xb = *(const float4*)(gxr + 4);
  stA8(Ab0, row, d0, xa); stA8(Ab0, row, d0 + 4, xb);
  {
    const char* src = B2 + cg * 4096 + tid * 16;
    gll16(src, Bb0 + tid * 16);
    gll16(src + 16384, Bb0 + 4096 + tid * 16);
  }
  xa = *(const float4*)(gxr + 32);
  xb = *(const float4*)(gxr + 36);

#pragma unroll 1
  for (int c = 0; c < 16; ++c) {
    const int p = c & 1;
    char* Bc = p ? Bb1 : Bb0;  char* Bn = p ? Bb0 : Bb1;
    char* Ac = p ? Ab1 : Ab0;  char* An = p ? Ab0 : Ab1;
    __syncthreads();
    if (c < 15) {
      const char* src = B2 + (size_t)(c + 1) * 32768 + cg * 4096 + tid * 16;
      gll16(src, Bn + tid * 16);
      gll16(src + 16384, Bn + 4096 + tid * 16);
    }
    float4 xna = xa, xnb = xb;
    if (c < 14) {
      xna = *(const float4*)(gxr + (c + 2) * 32);
      xnb = *(const float4*)(gxr + (c + 2) * 32 + 4);
    }
    if (c < 15) { stA8(An, row, d0, xa); stA8(An, row, d0 + 4, xb); }

    const int lo16 = lane * 16;
    i32x4 ah0 = *(const i32x4*)(Ac + lo16);
    i32x4 ah1 = *(const i32x4*)(Ac + 1024 + lo16);
    i32x4 al0 = *(const i32x4*)(Ac + 2048 + lo16);
    i32x4 al1 = *(const i32x4*)(Ac + 3072 + lo16);
    i32x4 bh = *(const i32x4*)(Bc + w * 1024 + lo16);
    i32x4 bl = *(const i32x4*)(Bc + 4096 + w * 1024 + lo16);
    MFMA_I8(k1[0], ah0, bh);
    MFMA_I8(k2[0], ah0, bl);
    MFMA_I8(k2[0], al0, bh);
    MFMA_I8(k1[1], ah1, bh);
    MFMA_I8(k2[1], ah1, bl);
    MFMA_I8(k2[1], al1, bh);
    xa = xna; xb = xnb;
  }

  // epilogue: rowsum * q_sum over wave's 32 cols, fold 4 waves
  const int b = tile >> 6;
  const int col = cg * 128 + w * 32 + l31;
  const float qs = q_sum[b * 512 + col];
  const float bkc = bk[col];
  __syncthreads();
#pragma unroll
  for (int mt = 0; mt < 2; ++mt)
#pragma unroll
    for (int r = 0; r < 16; ++r) {
      float pre = __builtin_fmaf((float)k1[mt][r], SC1,
                  __builtin_fmaf((float)k2[mt][r], SC2, bkc));
      float s = ftanh(pre) * qs;
#pragma unroll
      for (int off = 1; off <= 16; off <<= 1) s += __shfl_xor(s, off);
      if (l31 == 0) redk[w * 64 + mt * 32 + (r & 3) + 8 * (r >> 2) + 4 * hs] = s;
    }
  __syncthreads();
  if (tid < 64) {
    float s = redk[tid] + redk[64 + tid] + redk[128 + tid] + redk[192 + tid];
    spart[(size_t)cg * 65536 + (size_t)tile * 64 + tid] = s;
  }
}

// q_sum[b][e] = sum of the batch's 64 tile partials (64-row tiles)
__global__ void reduce_q(const float* __restrict__ qpart, float* __restrict__ q_sum) {
  int b = blockIdx.x, e = threadIdx.x;
  const float* p = qpart + (size_t)b * 64 * 512 + e;
  float s = 0.f;
#pragma unroll 4
  for (int j = 0; j < 64; ++j) s += p[j * 512];
  q_sum[b * 512 + e] = s;
}

// per-batch masked softmax over scaled scores (4 planes), times sv (4 planes)
__global__ void softmax_out(const float* __restrict__ spart,
                            const float* __restrict__ vpart,
                            const int* __restrict__ lens,
                            float* __restrict__ out) {
  const int b = blockIdx.x, tid = threadIdx.x;   // 256
  const int lane = tid & 63, wid = tid >> 6;
  const int len = lens[b];
  const float scale = 0.04419417382415922f;      // 1/sqrt(512)
  __shared__ float sb[4], sb2[4];

  float sreg[16], svreg[16];
#pragma unroll
  for (int j = 0; j < 16; ++j) {
    size_t l = (size_t)b * 4096 + tid + j * 256;
    sreg[j] = (spart[l] + spart[65536 + l] + spart[131072 + l] + spart[196608 + l]) * scale;
    svreg[j] = vpart[l] + vpart[65536 + l] + vpart[131072 + l] + vpart[196608 + l];
  }

  float m = -1e30f;
#pragma unroll
  for (int j = 0; j < 16; ++j)
    if (tid + j * 256 < len) m = fmaxf(m, sreg[j]);
#pragma unroll
  for (int off = 32; off >= 1; off >>= 1) m = fmaxf(m, __shfl_xor(m, off));
  if (lane == 0) sb[wid] = m;
  __syncthreads();
  m = fmaxf(fmaxf(sb[0], sb[1]), fmaxf(sb[2], sb[3]));

  float s = 0.f;
#pragma unroll
  for (int j = 0; j < 16; ++j)
    if (tid + j * 256 < len) s += expf(sreg[j] - m);
#pragma unroll
  for (int off = 32; off >= 1; off >>= 1) s += __shfl_xor(s, off);
  if (lane == 0) sb2[wid] = s;
  __syncthreads();
  const float inv = 1.f / (sb2[0] + sb2[1] + sb2[2] + sb2[3]);

  float* ob = out + (size_t)b * 4096;
#pragma unroll
  for (int j = 0; j < 16; ++j) {
    int l = tid + j * 256;
    ob[l] = (l < len) ? svreg[j] * expf(sreg[j] - m) * inv : 0.0f;
  }
}

extern "C" void kernel_launch(void* const* d_in, const int* in_sizes, int n_in,
                              void* d_out, int out_size, void* d_ws, size_t ws_size,
                              hipStream_t stream) {
  const float* x  = (const float*)d_in[0];
  const float* Wk = (const float*)d_in[1];
  const float* bk = (const float*)d_in[2];
  const float* Wq = (const float*)d_in[3];
  const float* bq = (const float*)d_in[4];
  const float* Wv = (const float*)d_in[5];
  const float* bv = (const float*)d_in[6];
  const int* lens = (const int*)d_in[7];
  float* out = (float*)d_out;

  char* ws = (char*)d_ws;
  char*  B1     = ws;                          // 1 MB   (Q+V W pack)
  char*  B2     = ws + 1048576;                // 512 KB (K W pack)
  float* qpart  = (float*)(ws + 1572864);      // [1024][512] f32 = 2 MB
  float* q_sum  = (float*)(ws + 3670016);      // [16][512] = 32 KB
  float* vpart  = (float*)(ws + 3702784);      // [4][65536] = 1 MB
  float* spart  = (float*)(ws + 4751360);      // [4][65536] = 1 MB

  prep_w<<<384, 256, 0, stream>>>(Wq, Wk, Wv, B1, B2);
  pass_q<<<4096, 256, 24576, stream>>>(x, B1, bq, qpart);
  pass_v<<<4096, 256, 25600, stream>>>(x, B1, bv, vpart);
  reduce_q<<<16, 512, 0, stream>>>(qpart, q_sum);
  pass_k<<<4096, 256, 25600, stream>>>(x, B2, bk, q_sum, spart);
  softmax_out<<<16, 256, 0, stream>>>(spart, vpart, lens, out);
}

// Round 13
// 263.526 us; speedup vs baseline: 1.1406x; 1.1406x over previous
//
#include <hip/hip_runtime.h>
#include <hip/hip_bf16.h>

typedef __attribute__((ext_vector_type(4)))  int   i32x4;
typedef __attribute__((ext_vector_type(16))) int   i32x16;
typedef __attribute__((ext_vector_type(16))) float f32x16;
typedef __attribute__((ext_vector_type(8)))  short short8;

#define SC1 (1.0f/4096.0f)     // xh*wh scale: (1/16)*(1/256)
#define SC2 (1.0f/524288.0f)   // cross terms: (1/16)*(1/32768) == (1/2048)*(1/256)

static __device__ __forceinline__ float ftanh(float x) {
  float e = __builtin_amdgcn_exp2f(x * 2.885390081777927f);
  return 1.0f - 2.0f * __builtin_amdgcn_rcpf(e + 1.0f);
}
static __device__ __forceinline__ unsigned short bf16_rn(float f) {
  unsigned u = __float_as_uint(f);
  u += 0x7FFFu + ((u >> 16) & 1u);
  return (unsigned short)(u >> 16);
}
// x ~= hi/sc + lo/(sc*losc); rne via magic-add. Proven round 6.
static __device__ __forceinline__ void quant2(float x, float sc, float inv, float losc,
                                              int& hi, int& lo) {
  float t  = __builtin_fmaf(x, sc, 12582912.0f);
  hi = __float_as_int(t) - 0x4B400000;
  float hf = t - 12582912.0f;
  float r  = __builtin_fmaf(hf, -inv, x);
  float t2 = __builtin_fmaf(r, losc, 12582912.0f);
  lo = __float_as_int(t2) - 0x4B400000;
}
static __device__ __forceinline__ void gll16(const void* g, void* l) {
  __builtin_amdgcn_global_load_lds((const __attribute__((address_space(1))) unsigned int*)g,
                                   (__attribute__((address_space(3))) unsigned int*)l, 16, 0, 0);
}
#define MFMA_I8(ACC, A, B) \
  asm("v_mfma_i32_32x32x32_i8 %0, %1, %2, %0" : "+v"(ACC) : "v"(A), "v"(B))

// ---------------------------------------------------------------------------
// prep_w (verbatim round 6): pack W into chunked global_load_lds-ready streams.
// B1 per chunk kc (64KB): [Q-hi 16KB][Q-lo 16KB][V-bf16 32KB]
//   Q: byte = kc*65536 + sel*16384 + (nt*64+lane)*16 + j
//      value W[col = nt*32+(lane&31)][k = kc*32+(lane>>5)*16+j]
//   V: byte = kc*65536 + 32768 + ((nt*2+ks)*64+lane)*16 + j*2 (8 bf16)
// B2 per chunk (32KB): [K-hi 16KB][K-lo 16KB], same scheme.
// ---------------------------------------------------------------------------
__global__ void prep_w(const float* __restrict__ Wq, const float* __restrict__ Wk,
                       const float* __restrict__ Wv,
                       char* __restrict__ B1, char* __restrict__ B2) {
  int gid = blockIdx.x * 256 + threadIdx.x;   // 0..98303
  if (gid < 65536) {
    int chunk = gid >> 12, g = gid & 4095;
    char* dst = B1 + chunk * 65536 + g * 16;
    if (g < 2048) {
      int sel = g >> 10;
      int gg = g & 1023, nt = gg >> 6, lane = gg & 63;
      const float* src = Wq + (size_t)(nt * 32 + (lane & 31)) * 512 + chunk * 32 + (lane >> 5) * 16;
      union { char b[16]; i32x4 v; } ob;
#pragma unroll
      for (int j = 0; j < 16; ++j) {
        int h, l; quant2(src[j], 256.f, 1.f / 256.f, 32768.f, h, l);
        ob.b[j] = (char)(sel ? l : h);
      }
      *(i32x4*)dst = ob.v;
    } else {
      int gg = g - 2048, nt = gg >> 7, ks = (gg >> 6) & 1, lane = gg & 63;
      const float* src = Wv + (size_t)(nt * 32 + (lane & 31)) * 512 + chunk * 32 + ks * 16 + (lane >> 5) * 8;
      union { unsigned short s[8]; i32x4 v; } ob;
#pragma unroll
      for (int j = 0; j < 8; ++j) ob.s[j] = bf16_rn(src[j]);
      *(i32x4*)dst = ob.v;
    }
  } else {
    int gid2 = gid - 65536;
    int chunk = gid2 >> 11, g = gid2 & 2047;
    char* dst = B2 + chunk * 32768 + g * 16;
    int sel = g >> 10, gg = g & 1023, nt = gg >> 6, lane = gg & 63;
    const float* src = Wk + (size_t)(nt * 32 + (lane & 31)) * 512 + chunk * 32 + (lane >> 5) * 16;
    union { char b[16]; i32x4 v; } ob;
#pragma unroll
    for (int j = 0; j < 16; ++j) {
      int h, l; quant2(src[j], 256.f, 1.f / 256.f, 32768.f, h, l);
      ob.b[j] = (char)(sel ? l : h);
    }
    *(i32x4*)dst = ob.v;
  }
}

// ---- A-staging, 32-row chunk (mt=0 plane of the proven R6 layout). ----
// i8: hi byte (ks32*32+row)*16 + (d0&15); lo plane at +1024. Reader: Ac+lane*16,
// Ac+1024+lane*16 (lane = hs*32 + l31 -> row=l31, k-half=hs). Same constants
// both sides.
static __device__ __forceinline__ void stA8_32(char* Ab, int row, int d0, float4 xv) {
  int h0, l0, h1, l1, h2, l2, h3, l3;
  quant2(xv.x, 16.f, 0.0625f, 2048.f, h0, l0);
  quant2(xv.y, 16.f, 0.0625f, 2048.f, h1, l1);
  quant2(xv.z, 16.f, 0.0625f, 2048.f, h2, l2);
  quant2(xv.w, 16.f, 0.0625f, 2048.f, h3, l3);
  unsigned wh = (h0 & 255) | ((h1 & 255) << 8) | ((h2 & 255) << 16) | ((unsigned)(h3 & 255) << 24);
  unsigned wl = (l0 & 255) | ((l1 & 255) << 8) | ((l2 & 255) << 16) | ((unsigned)(l3 & 255) << 24);
  const int lane8 = (d0 >> 4) * 32 + row, j = d0 & 15;
  *(unsigned*)(Ab + lane8 * 16 + j) = wh;          // hi plane (1KB)
  *(unsigned*)(Ab + 1024 + lane8 * 16 + j) = wl;   // lo plane (1KB)
}
// bf16 (V): (ks*64 + hs8*32 + row)*16 + j8*2, 2KB total; reader Ac+ks*1024+lane*16.
static __device__ __forceinline__ void stAv_32(char* Ab, int row, int d0, float4 xv) {
  unsigned long long b0 = bf16_rn(xv.x), b1 = bf16_rn(xv.y), b2 = bf16_rn(xv.z), b3 = bf16_rn(xv.w);
  unsigned long long vv = b0 | (b1 << 16) | (b2 << 32) | (b3 << 48);
  const int ks = d0 >> 4, rem = d0 & 15, hs8 = rem >> 3, j8 = rem & 7;
  *(unsigned long long*)(Ab + (ks * 64 + hs8 * 32 + row) * 16 + j8 * 2) = vv;
}

// ---------------------------------------------------------------------------
// pass_q: Q (i8 2-term, colsum). Block = 32 rows x 512 cols, 512 thr, 8 waves;
// wave w owns cols [w*64, w*64+64). acc 64 regs -> launch_bounds(512,4) ->
// 2 blocks/CU, 4 waves/SIMD. R11 dbuf skeleton verbatim; x read once/tile.
// ---------------------------------------------------------------------------
__global__ __launch_bounds__(512, 4) void pass_q(
    const float* __restrict__ x, const char* __restrict__ B1,
    const float* __restrict__ bq, float* __restrict__ qpart) {
  extern __shared__ char smem[];
  char* Bb0 = smem;          char* Bb1 = smem + 32768;   // B dbuf 2x32KB
  char* Ab0 = smem + 65536;  char* Ab1 = smem + 67584;   // A dbuf 2x2KB

  const int tid = threadIdx.x, lane = tid & 63, w = tid >> 6;
  const int l31 = lane & 31;
  const int tile = blockIdx.x;
  const int row = tid >> 3, d0 = (tid & 7) * 4;          // staging (tid<256)
  const float* gxr = x + ((size_t)tile * 32 + row) * 512 + d0;

  i32x16 q1[2] = {}, q2[2] = {};
  float4 xcur = {};

  // prologue: chunk 0 staged; chunk 1 in regs
  if (tid < 256) { xcur = *(const float4*)(gxr); stA8_32(Ab0, row, d0, xcur); }
  {
    const char* src = B1 + tid * 16;
    char* dst = Bb0 + tid * 16;
#pragma unroll
    for (int i = 0; i < 4; ++i) gll16(src + i * 8192, dst + i * 8192);
  }
  if (tid < 256) xcur = *(const float4*)(gxr + 32);

#pragma unroll 1
  for (int c = 0; c < 16; ++c) {
    const int p = c & 1;
    char* Bc = p ? Bb1 : Bb0;  char* Bn = p ? Bb0 : Bb1;
    char* Ac = p ? Ab1 : Ab0;  char* An = p ? Ab0 : Ab1;
    __syncthreads();
    if (c < 15) {
      const char* src = B1 + (size_t)(c + 1) * 65536 + tid * 16;
      char* dst = Bn + tid * 16;
#pragma unroll
      for (int i = 0; i < 4; ++i) gll16(src + i * 8192, dst + i * 8192);
    }
    float4 xnext = xcur;
    if (tid < 256) {
      if (c < 14) xnext = *(const float4*)(gxr + (c + 2) * 32);
      if (c < 15) stA8_32(An, row, d0, xcur);
    }

    const int lo16 = lane * 16;
    i32x4 ah = *(const i32x4*)(Ac + lo16);
    i32x4 al = *(const i32x4*)(Ac + 1024 + lo16);
#pragma unroll
    for (int nn = 0; nn < 2; ++nn) {
      const int nt = w * 2 + nn;
      i32x4 bh = *(const i32x4*)(Bc + nt * 1024 + lo16);
      i32x4 bl = *(const i32x4*)(Bc + 16384 + nt * 1024 + lo16);
      MFMA_I8(q1[nn], ah, bh);
      MFMA_I8(q2[nn], ah, bl);
      MFMA_I8(q2[nn], al, bh);
    }
    xcur = xnext;
  }

  // epilogue: colsum; cols private per wave (verbatim R11, mt dropped)
#pragma unroll
  for (int nn = 0; nn < 2; ++nn) {
    const int col = (w * 2 + nn) * 32 + l31;
    const float bc = bq[col];
    float cs = 0.f;
#pragma unroll
    for (int r = 0; r < 16; ++r)
      cs += ftanh(__builtin_fmaf((float)q1[nn][r], SC1,
                  __builtin_fmaf((float)q2[nn][r], SC2, bc)));
    cs += __shfl_xor(cs, 32);
    if (lane < 32) qpart[(size_t)tile * 512 + col] = cs;
  }
}

// ---------------------------------------------------------------------------
// pass_v: V (bf16 1-term, rowsum). Same geometry; acc 32 regs.
// ---------------------------------------------------------------------------
__global__ __launch_bounds__(512, 4) void pass_v(
    const float* __restrict__ x, const char* __restrict__ B1,
    const float* __restrict__ bv, float* __restrict__ svout) {
  extern __shared__ char smem[];
  char* Bb0 = smem;          char* Bb1 = smem + 32768;   // B dbuf 2x32KB
  char* Ab0 = smem + 65536;  char* Ab1 = smem + 67584;   // A dbuf 2x2KB
  float* redv = (float*)(smem + 69632);                  // [8][32] = 1KB

  const int tid = threadIdx.x, lane = tid & 63, w = tid >> 6;
  const int l31 = lane & 31, hs = lane >> 5;
  const int tile = blockIdx.x;
  const int row = tid >> 3, d0 = (tid & 7) * 4;
  const float* gxr = x + ((size_t)tile * 32 + row) * 512 + d0;

  f32x16 accv[2] = {};
  float4 xcur = {};

  if (tid < 256) { xcur = *(const float4*)(gxr); stAv_32(Ab0, row, d0, xcur); }
  {
    const char* src = B1 + 32768 + tid * 16;
    char* dst = Bb0 + tid * 16;
#pragma unroll
    for (int i = 0; i < 4; ++i) gll16(src + i * 8192, dst + i * 8192);
  }
  if (tid < 256) xcur = *(const float4*)(gxr + 32);

#pragma unroll 1
  for (int c = 0; c < 16; ++c) {
    const int p = c & 1;
    char* Bc = p ? Bb1 : Bb0;  char* Bn = p ? Bb0 : Bb1;
    char* Ac = p ? Ab1 : Ab0;  char* An = p ? Ab0 : Ab1;
    __syncthreads();
    if (c < 15) {
      const char* src = B1 + (size_t)(c + 1) * 65536 + 32768 + tid * 16;
      char* dst = Bn + tid * 16;
#pragma unroll
      for (int i = 0; i < 4; ++i) gll16(src + i * 8192, dst + i * 8192);
    }
    float4 xnext = xcur;
    if (tid < 256) {
      if (c < 14) xnext = *(const float4*)(gxr + (c + 2) * 32);
      if (c < 15) stAv_32(An, row, d0, xcur);
    }

    const int lo16 = lane * 16;
#pragma unroll
    for (int ks = 0; ks < 2; ++ks) {
      short8 av = *(const short8*)(Ac + ks * 1024 + lo16);
#pragma unroll
      for (int nn = 0; nn < 2; ++nn) {
        const int nt = w * 2 + nn;
        short8 bvf = *(const short8*)(Bc + (nt * 2 + ks) * 1024 + lo16);
        accv[nn] = __builtin_amdgcn_mfma_f32_32x32x16_bf16(av, bvf, accv[nn], 0, 0, 0);
      }
    }
    xcur = xnext;
  }

  // epilogue: rowsum over wave's 64 cols, fold 8 waves (verbatim R11, mt=0)
  const float bv0 = bv[(w * 2 + 0) * 32 + l31];
  const float bv1 = bv[(w * 2 + 1) * 32 + l31];
  __syncthreads();
#pragma unroll
  for (int r = 0; r < 16; ++r) {
    float s = ftanh(accv[0][r] + bv0) + ftanh(accv[1][r] + bv1);
#pragma unroll
    for (int off = 1; off <= 16; off <<= 1) s += __shfl_xor(s, off);
    if (l31 == 0) redv[w * 32 + (r & 3) + 8 * (r >> 2) + 4 * hs] = s;
  }
  __syncthreads();
  if (tid < 32) {
    float s = 0.f;
#pragma unroll
    for (int j = 0; j < 8; ++j) s += redv[j * 32 + tid];
    svout[(size_t)tile * 32 + tid] = s;
  }
}

// ---------------------------------------------------------------------------
// pass_k: K (i8 2-term, rowsum * q_sum). Same geometry as pass_q.
// ---------------------------------------------------------------------------
__global__ __launch_bounds__(512, 4) void pass_k(
    const float* __restrict__ x, const char* __restrict__ B2,
    const float* __restrict__ bk, const float* __restrict__ q_sum,
    float* __restrict__ scores) {
  extern __shared__ char smem[];
  char* Bb0 = smem;          char* Bb1 = smem + 32768;
  char* Ab0 = smem + 65536;  char* Ab1 = smem + 67584;
  float* redk = (float*)(smem + 69632);                  // [8][32]

  const int tid = threadIdx.x, lane = tid & 63, w = tid >> 6;
  const int l31 = lane & 31, hs = lane >> 5;
  const int tile = blockIdx.x;
  const int row = tid >> 3, d0 = (tid & 7) * 4;
  const float* gxr = x + ((size_t)tile * 32 + row) * 512 + d0;

  i32x16 k1[2] = {}, k2[2] = {};
  float4 xcur = {};

  if (tid < 256) { xcur = *(const float4*)(gxr); stA8_32(Ab0, row, d0, xcur); }
  {
    const char* src = B2 + tid * 16;
    char* dst = Bb0 + tid * 16;
#pragma unroll
    for (int i = 0; i < 4; ++i) gll16(src + i * 8192, dst + i * 8192);
  }
  if (tid < 256) xcur = *(const float4*)(gxr + 32);

#pragma unroll 1
  for (int c = 0; c < 16; ++c) {
    const int p = c & 1;
    char* Bc = p ? Bb1 : Bb0;  char* Bn = p ? Bb0 : Bb1;
    char* Ac = p ? Ab1 : Ab0;  char* An = p ? Ab0 : Ab1;
    __syncthreads();
    if (c < 15) {
      const char* src = B2 + (size_t)(c + 1) * 32768 + tid * 16;
      char* dst = Bn + tid * 16;
#pragma unroll
      for (int i = 0; i < 4; ++i) gll16(src + i * 8192, dst + i * 8192);
    }
    float4 xnext = xcur;
    if (tid < 256) {
      if (c < 14) xnext = *(const float4*)(gxr + (c + 2) * 32);
      if (c < 15) stA8_32(An, row, d0, xcur);
    }

    const int lo16 = lane * 16;
    i32x4 ah = *(const i32x4*)(Ac + lo16);
    i32x4 al = *(const i32x4*)(Ac + 1024 + lo16);
#pragma unroll
    for (int nn = 0; nn < 2; ++nn) {
      const int nt = w * 2 + nn;
      i32x4 bh = *(const i32x4*)(Bc + nt * 1024 + lo16);
      i32x4 bl = *(const i32x4*)(Bc + 16384 + nt * 1024 + lo16);
      MFMA_I8(k1[nn], ah, bh);
      MFMA_I8(k2[nn], ah, bl);
      MFMA_I8(k2[nn], al, bh);
    }
    xcur = xnext;
  }

  // epilogue: rowsum * q_sum over wave's 64 cols, fold 8 waves
  const int b = tile >> 7;   // 128 tiles per batch
  const int c0 = (w * 2 + 0) * 32 + l31, c1 = (w * 2 + 1) * 32 + l31;
  const float qs0 = q_sum[b * 512 + c0], qs1 = q_sum[b * 512 + c1];
  const float bk0 = bk[c0], bk1 = bk[c1];
  __syncthreads();
#pragma unroll
  for (int r = 0; r < 16; ++r) {
    float p0 = __builtin_fmaf((float)k1[0][r], SC1,
               __builtin_fmaf((float)k2[0][r], SC2, bk0));
    float p1 = __builtin_fmaf((float)k1[1][r], SC1,
               __builtin_fmaf((float)k2[1][r], SC2, bk1));
    float s = ftanh(p0) * qs0 + ftanh(p1) * qs1;
#pragma unroll
    for (int off = 1; off <= 16; off <<= 1) s += __shfl_xor(s, off);
    if (l31 == 0) redk[w * 32 + (r & 3) + 8 * (r >> 2) + 4 * hs] = s;
  }
  __syncthreads();
  if (tid < 32) {
    float s = 0.f;
#pragma unroll
    for (int j = 0; j < 8; ++j) s += redk[j * 32 + tid];
    scores[(size_t)tile * 32 + tid] = s;
  }
}

// q_sum[b][e] = sum of the batch's 128 tile partials (32-row tiles)
__global__ void reduce_q(const float* __restrict__ qpart, float* __restrict__ q_sum) {
  int b = blockIdx.x, e = threadIdx.x;
  const float* p = qpart + (size_t)b * 128 * 512 + e;
  float s = 0.f;
#pragma unroll 4
  for (int j = 0; j < 128; ++j) s += p[j * 512];
  q_sum[b * 512 + e] = s;
}

// per-batch masked softmax over scaled scores, times sv
__global__ void softmax_out(const float* __restrict__ scores,
                            const float* __restrict__ sv,
                            const int* __restrict__ lens,
                            float* __restrict__ out) {
  const int b = blockIdx.x, tid = threadIdx.x;   // 256
  const int lane = tid & 63, wid = tid >> 6;
  const int len = lens[b];
  const float scale = 0.04419417382415922f;      // 1/sqrt(512)
  __shared__ float sb[4], sb2[4];

  float sreg[16];
  const float* sc = scores + (size_t)b * 4096;
#pragma unroll
  for (int j = 0; j < 16; ++j) sreg[j] = sc[tid + j * 256] * scale;

  float m = -1e30f;
#pragma unroll
  for (int j = 0; j < 16; ++j)
    if (tid + j * 256 < len) m = fmaxf(m, sreg[j]);
#pragma unroll
  for (int off = 32; off >= 1; off >>= 1) m = fmaxf(m, __shfl_xor(m, off));
  if (lane == 0) sb[wid] = m;
  __syncthreads();
  m = fmaxf(fmaxf(sb[0], sb[1]), fmaxf(sb[2], sb[3]));

  float s = 0.f;
#pragma unroll
  for (int j = 0; j < 16; ++j)
    if (tid + j * 256 < len) s += expf(sreg[j] - m);
#pragma unroll
  for (int off = 32; off >= 1; off >>= 1) s += __shfl_xor(s, off);
  if (lane == 0) sb2[wid] = s;
  __syncthreads();
  const float inv = 1.f / (sb2[0] + sb2[1] + sb2[2] + sb2[3]);

  const float* svb = sv + (size_t)b * 4096;
  float* ob = out + (size_t)b * 4096;
#pragma unroll
  for (int j = 0; j < 16; ++j) {
    int l = tid + j * 256;
    ob[l] = (l < len) ? svb[l] * expf(sreg[j] - m) * inv : 0.0f;
  }
}

extern "C" void kernel_launch(void* const* d_in, const int* in_sizes, int n_in,
                              void* d_out, int out_size, void* d_ws, size_t ws_size,
                              hipStream_t stream) {
  const float* x  = (const float*)d_in[0];
  const float* Wk = (const float*)d_in[1];
  const float* bk = (const float*)d_in[2];
  const float* Wq = (const float*)d_in[3];
  const float* bq = (const float*)d_in[4];
  const float* Wv = (const float*)d_in[5];
  const float* bv = (const float*)d_in[6];
  const int* lens = (const int*)d_in[7];
  float* out = (float*)d_out;

  char* ws = (char*)d_ws;
  char*  B1     = ws;                          // 1 MB   (Q+V W pack)
  char*  B2     = ws + 1048576;                // 512 KB (K W pack)
  float* qpart  = (float*)(ws + 1572864);      // [2048][512] f32 = 4 MB
  float* q_sum  = (float*)(ws + 5767168);      // [16][512] = 32 KB
  float* svbuf  = (float*)(ws + 5799936);      // [65536] = 256 KB
  float* scores = (float*)(ws + 6062080);      // [65536] = 256 KB

  prep_w<<<384, 256, 0, stream>>>(Wq, Wk, Wv, B1, B2);
  pass_q<<<2048, 512, 69632, stream>>>(x, B1, bq, qpart);
  pass_v<<<2048, 512, 70656, stream>>>(x, B1, bv, svbuf);
  reduce_q<<<16, 512, 0, stream>>>(qpart, q_sum);
  pass_k<<<2048, 512, 70656, stream>>>(x, B2, bk, q_sum, scores);
  softmax_out<<<16, 256, 0, stream>>>(scores, svbuf, lens, out);
}

// Round 14
// 235.319 us; speedup vs baseline: 1.2773x; 1.1199x over previous
//
#include <hip/hip_runtime.h>
#include <hip/hip_bf16.h>

typedef __attribute__((ext_vector_type(4)))  int   i32x4;
typedef __attribute__((ext_vector_type(16))) int   i32x16;
typedef __attribute__((ext_vector_type(16))) float f32x16;
typedef __attribute__((ext_vector_type(8)))  short short8;

#define SC1 (1.0f/4096.0f)     // xh*wh scale: (1/16)*(1/256)
#define SC2 (1.0f/524288.0f)   // cross terms: (1/16)*(1/32768) == (1/2048)*(1/256)

static __device__ __forceinline__ float ftanh(float x) {
  float e = __builtin_amdgcn_exp2f(x * 2.885390081777927f);
  return 1.0f - 2.0f * __builtin_amdgcn_rcpf(e + 1.0f);
}
static __device__ __forceinline__ unsigned short bf16_rn(float f) {
  unsigned u = __float_as_uint(f);
  u += 0x7FFFu + ((u >> 16) & 1u);
  return (unsigned short)(u >> 16);
}
// x ~= hi/sc + lo/(sc*losc); rne via magic-add. Proven round 6.
static __device__ __forceinline__ void quant2(float x, float sc, float inv, float losc,
                                              int& hi, int& lo) {
  float t  = __builtin_fmaf(x, sc, 12582912.0f);
  hi = __float_as_int(t) - 0x4B400000;
  float hf = t - 12582912.0f;
  float r  = __builtin_fmaf(hf, -inv, x);
  float t2 = __builtin_fmaf(r, losc, 12582912.0f);
  lo = __float_as_int(t2) - 0x4B400000;
}
static __device__ __forceinline__ void gll16(const void* g, void* l) {
  __builtin_amdgcn_global_load_lds((const __attribute__((address_space(1))) unsigned int*)g,
                                   (__attribute__((address_space(3))) unsigned int*)l, 16, 0, 0);
}
#define MFMA_I8(ACC, A, B) \
  asm("v_mfma_i32_32x32x32_i8 %0, %1, %2, %0" : "+v"(ACC) : "v"(A), "v"(B))

// ---------------------------------------------------------------------------
// prep_w (verbatim round 6): pack W into chunked global_load_lds-ready streams.
// B1 per chunk kc (64KB): [Q-hi 16KB][Q-lo 16KB][V-bf16 32KB]
//   Q: byte = kc*65536 + sel*16384 + (nt*64+lane)*16 + j
//      value W[col = nt*32+(lane&31)][k = kc*32+(lane>>5)*16+j]
//   V: byte = kc*65536 + 32768 + ((nt*2+ks)*64+lane)*16 + j*2 (8 bf16)
// B2 per chunk (32KB): [K-hi 16KB][K-lo 16KB], same scheme.
// ---------------------------------------------------------------------------
__global__ void prep_w(const float* __restrict__ Wq, const float* __restrict__ Wk,
                       const float* __restrict__ Wv,
                       char* __restrict__ B1, char* __restrict__ B2) {
  int gid = blockIdx.x * 256 + threadIdx.x;   // 0..98303
  if (gid < 65536) {
    int chunk = gid >> 12, g = gid & 4095;
    char* dst = B1 + chunk * 65536 + g * 16;
    if (g < 2048) {
      int sel = g >> 10;
      int gg = g & 1023, nt = gg >> 6, lane = gg & 63;
      const float* src = Wq + (size_t)(nt * 32 + (lane & 31)) * 512 + chunk * 32 + (lane >> 5) * 16;
      union { char b[16]; i32x4 v; } ob;
#pragma unroll
      for (int j = 0; j < 16; ++j) {
        int h, l; quant2(src[j], 256.f, 1.f / 256.f, 32768.f, h, l);
        ob.b[j] = (char)(sel ? l : h);
      }
      *(i32x4*)dst = ob.v;
    } else {
      int gg = g - 2048, nt = gg >> 7, ks = (gg >> 6) & 1, lane = gg & 63;
      const float* src = Wv + (size_t)(nt * 32 + (lane & 31)) * 512 + chunk * 32 + ks * 16 + (lane >> 5) * 8;
      union { unsigned short s[8]; i32x4 v; } ob;
#pragma unroll
      for (int j = 0; j < 8; ++j) ob.s[j] = bf16_rn(src[j]);
      *(i32x4*)dst = ob.v;
    }
  } else {
    int gid2 = gid - 65536;
    int chunk = gid2 >> 11, g = gid2 & 2047;
    char* dst = B2 + chunk * 32768 + g * 16;
    int sel = g >> 10, gg = g & 1023, nt = gg >> 6, lane = gg & 63;
    const float* src = Wk + (size_t)(nt * 32 + (lane & 31)) * 512 + chunk * 32 + (lane >> 5) * 16;
    union { char b[16]; i32x4 v; } ob;
#pragma unroll
    for (int j = 0; j < 16; ++j) {
      int h, l; quant2(src[j], 256.f, 1.f / 256.f, 32768.f, h, l);
      ob.b[j] = (char)(sel ? l : h);
    }
    *(i32x4*)dst = ob.v;
  }
}

// ---- A-staging (verbatim R6/R11): thread (row=tid>>3, d0=(tid&7)*4), 64x32
// chunk -> i8 hi/lo frag planes (4KB: hi mt0/mt1 @0/1024, lo @2048/3072). ----
static __device__ __forceinline__ void stageAi8(char* Ab, int row, int d0, float4 xv) {
  const int mt = row >> 5, l31 = row & 31;
  int h0, l0, h1, l1, h2, l2, h3, l3;
  quant2(xv.x, 16.f, 0.0625f, 2048.f, h0, l0);
  quant2(xv.y, 16.f, 0.0625f, 2048.f, h1, l1);
  quant2(xv.z, 16.f, 0.0625f, 2048.f, h2, l2);
  quant2(xv.w, 16.f, 0.0625f, 2048.f, h3, l3);
  unsigned wh = (h0 & 255) | ((h1 & 255) << 8) | ((h2 & 255) << 16) | ((unsigned)(h3 & 255) << 24);
  unsigned wl = (l0 & 255) | ((l1 & 255) << 8) | ((l2 & 255) << 16) | ((unsigned)(l3 & 255) << 24);
  const int lane8 = (d0 >> 4) * 32 + l31, j = d0 & 15;
  *(unsigned*)(Ab + (mt * 64 + lane8) * 16 + j) = wh;
  *(unsigned*)(Ab + 2048 + (mt * 64 + lane8) * 16 + j) = wl;
}
// bf16 (V) frag planes (4KB, (mt*2+ks) planes) -- verbatim R11 stageAv.
static __device__ __forceinline__ void stageAv(char* Ab, int row, int d0, float4 xv) {
  const int mt = row >> 5, l31 = row & 31;
  unsigned long long b0 = bf16_rn(xv.x), b1 = bf16_rn(xv.y), b2 = bf16_rn(xv.z), b3 = bf16_rn(xv.w);
  unsigned long long vv = b0 | (b1 << 16) | (b2 << 32) | (b3 << 48);
  const int ks = d0 >> 4, rem = d0 & 15, hs8 = rem >> 3, j8 = rem & 7;
  *(unsigned long long*)(Ab + ((mt * 2 + ks) * 64 + hs8 * 32 + l31) * 16 + j8 * 2) = vv;
}

// ---------------------------------------------------------------------------
// pass_q: Q (i8 2-term, colsum). Block = 64 rows x 512 cols, 1024 thr =
// 16 waves (2 mt x 8 ng); wave = 32r x 64c -> acc 64 regs -> 4 waves/SIMD.
// B-traffic halved vs 32-row blocks at the same waves/SIMD. Chunk-staggered
// start (bid&15) spreads L2 slice pressure. R11 dbuf skeleton verbatim.
// ---------------------------------------------------------------------------
__global__ __launch_bounds__(1024, 4) void pass_q(
    const float* __restrict__ x, const char* __restrict__ B1,
    const float* __restrict__ bq, float* __restrict__ qpart) {
  extern __shared__ char smem[];
  char* Bb0 = smem;          char* Bb1 = smem + 32768;   // B dbuf 2x32KB
  char* Ab0 = smem + 65536;  char* Ab1 = smem + 69632;   // A dbuf 2x4KB
  float* redq = (float*)(smem + 73728);                  // [2][512] = 4KB

  const int tid = threadIdx.x, lane = tid & 63, w = tid >> 6;  // w 0..15
  const int l31 = lane & 31;
  const int mt = w >> 3, ng = w & 7;
  const int tile = blockIdx.x;
  const int stag = tile & 15;
  const int row = tid >> 3, d0 = (tid & 7) * 4;          // staging (tid<512)
  const float* gxr = x + ((size_t)tile * 64 + row) * 512 + d0;

  i32x16 q1[2] = {}, q2[2] = {};
  float4 xcur = {};

  // prologue: chunk perm(0) staged; perm(1) in regs
  if (tid < 512) { xcur = *(const float4*)(gxr + stag * 32); stageAi8(Ab0, row, d0, xcur); }
  {
    const char* src = B1 + (size_t)stag * 65536 + tid * 16;
    gll16(src, Bb0 + tid * 16);
    gll16(src + 16384, Bb0 + 16384 + tid * 16);
  }
  if (tid < 512) xcur = *(const float4*)(gxr + (((stag + 1) & 15)) * 32);

#pragma unroll 1
  for (int c = 0; c < 16; ++c) {
    const int p = c & 1;
    char* Bc = p ? Bb1 : Bb0;  char* Bn = p ? Bb0 : Bb1;
    char* Ac = p ? Ab1 : Ab0;  char* An = p ? Ab0 : Ab1;
    __syncthreads();
    if (c < 15) {
      const char* src = B1 + (size_t)(((c + 1 + stag) & 15)) * 65536 + tid * 16;
      gll16(src, Bn + tid * 16);
      gll16(src + 16384, Bn + 16384 + tid * 16);
    }
    float4 xnext = xcur;
    if (tid < 512) {
      if (c < 14) xnext = *(const float4*)(gxr + (((c + 2 + stag) & 15)) * 32);
      if (c < 15) stageAi8(An, row, d0, xcur);
    }

    const int lo16 = lane * 16;
    i32x4 ah = *(const i32x4*)(Ac + mt * 1024 + lo16);
    i32x4 al = *(const i32x4*)(Ac + 2048 + mt * 1024 + lo16);
#pragma unroll
    for (int nn = 0; nn < 2; ++nn) {
      const int nt = ng * 2 + nn;
      i32x4 bh = *(const i32x4*)(Bc + nt * 1024 + lo16);
      i32x4 bl = *(const i32x4*)(Bc + 16384 + nt * 1024 + lo16);
      MFMA_I8(q1[nn], ah, bh);
      MFMA_I8(q2[nn], ah, bl);
      MFMA_I8(q2[nn], al, bh);
    }
    xcur = xnext;
  }

  // epilogue: per-mt colsum partial -> LDS fold across the 2 mt-waves
#pragma unroll
  for (int nn = 0; nn < 2; ++nn) {
    const int col = (ng * 2 + nn) * 32 + l31;
    const float bc = bq[col];
    float cs = 0.f;
#pragma unroll
    for (int r = 0; r < 16; ++r)
      cs += ftanh(__builtin_fmaf((float)q1[nn][r], SC1,
                  __builtin_fmaf((float)q2[nn][r], SC2, bc)));
    cs += __shfl_xor(cs, 32);
    if (lane < 32) redq[mt * 512 + col] = cs;
  }
  __syncthreads();
  if (tid < 512) qpart[(size_t)tile * 512 + tid] = redq[tid] + redq[512 + tid];
}

// ---------------------------------------------------------------------------
// pass_v: V (bf16 1-term, rowsum). Same geometry; acc 32 regs.
// ---------------------------------------------------------------------------
__global__ __launch_bounds__(1024, 4) void pass_v(
    const float* __restrict__ x, const char* __restrict__ B1,
    const float* __restrict__ bv, float* __restrict__ svout) {
  extern __shared__ char smem[];
  char* Bb0 = smem;          char* Bb1 = smem + 32768;
  char* Ab0 = smem + 65536;  char* Ab1 = smem + 69632;
  float* redv = (float*)(smem + 73728);                  // [8][64] = 2KB

  const int tid = threadIdx.x, lane = tid & 63, w = tid >> 6;
  const int l31 = lane & 31, hs = lane >> 5;
  const int mt = w >> 3, ng = w & 7;
  const int tile = blockIdx.x;
  const int stag = tile & 15;
  const int row = tid >> 3, d0 = (tid & 7) * 4;
  const float* gxr = x + ((size_t)tile * 64 + row) * 512 + d0;

  f32x16 accv[2] = {};
  float4 xcur = {};

  if (tid < 512) { xcur = *(const float4*)(gxr + stag * 32); stageAv(Ab0, row, d0, xcur); }
  {
    const char* src = B1 + (size_t)stag * 65536 + 32768 + tid * 16;
    gll16(src, Bb0 + tid * 16);
    gll16(src + 16384, Bb0 + 16384 + tid * 16);
  }
  if (tid < 512) xcur = *(const float4*)(gxr + (((stag + 1) & 15)) * 32);

#pragma unroll 1
  for (int c = 0; c < 16; ++c) {
    const int p = c & 1;
    char* Bc = p ? Bb1 : Bb0;  char* Bn = p ? Bb0 : Bb1;
    char* Ac = p ? Ab1 : Ab0;  char* An = p ? Ab0 : Ab1;
    __syncthreads();
    if (c < 15) {
      const char* src = B1 + (size_t)(((c + 1 + stag) & 15)) * 65536 + 32768 + tid * 16;
      gll16(src, Bn + tid * 16);
      gll16(src + 16384, Bn + 16384 + tid * 16);
    }
    float4 xnext = xcur;
    if (tid < 512) {
      if (c < 14) xnext = *(const float4*)(gxr + (((c + 2 + stag) & 15)) * 32);
      if (c < 15) stageAv(An, row, d0, xcur);
    }

    const int lo16 = lane * 16;
#pragma unroll
    for (int ks = 0; ks < 2; ++ks) {
      short8 av = *(const short8*)(Ac + (mt * 2 + ks) * 1024 + lo16);
#pragma unroll
      for (int nn = 0; nn < 2; ++nn) {
        const int nt = ng * 2 + nn;
        short8 bvf = *(const short8*)(Bc + (nt * 2 + ks) * 1024 + lo16);
        accv[nn] = __builtin_amdgcn_mfma_f32_32x32x16_bf16(av, bvf, accv[nn], 0, 0, 0);
      }
    }
    xcur = xnext;
  }

  // epilogue: rowsum over wave's 64 cols, fold 8 ng-waves
  const float bv0 = bv[(ng * 2 + 0) * 32 + l31];
  const float bv1 = bv[(ng * 2 + 1) * 32 + l31];
  __syncthreads();
#pragma unroll
  for (int r = 0; r < 16; ++r) {
    float s = ftanh(accv[0][r] + bv0) + ftanh(accv[1][r] + bv1);
#pragma unroll
    for (int off = 1; off <= 16; off <<= 1) s += __shfl_xor(s, off);
    if (l31 == 0) redv[ng * 64 + mt * 32 + (r & 3) + 8 * (r >> 2) + 4 * hs] = s;
  }
  __syncthreads();
  if (tid < 64) {
    float s = 0.f;
#pragma unroll
    for (int j = 0; j < 8; ++j) s += redv[j * 64 + tid];
    svout[(size_t)tile * 64 + tid] = s;
  }
}

// ---------------------------------------------------------------------------
// pass_k: K (i8 2-term, rowsum * q_sum). Same geometry as pass_q.
// ---------------------------------------------------------------------------
__global__ __launch_bounds__(1024, 4) void pass_k(
    const float* __restrict__ x, const char* __restrict__ B2,
    const float* __restrict__ bk, const float* __restrict__ q_sum,
    float* __restrict__ scores) {
  extern __shared__ char smem[];
  char* Bb0 = smem;          char* Bb1 = smem + 32768;
  char* Ab0 = smem + 65536;  char* Ab1 = smem + 69632;
  float* redk = (float*)(smem + 73728);                  // [8][64] = 2KB

  const int tid = threadIdx.x, lane = tid & 63, w = tid >> 6;
  const int l31 = lane & 31, hs = lane >> 5;
  const int mt = w >> 3, ng = w & 7;
  const int tile = blockIdx.x;
  const int stag = tile & 15;
  const int row = tid >> 3, d0 = (tid & 7) * 4;
  const float* gxr = x + ((size_t)tile * 64 + row) * 512 + d0;

  i32x16 k1[2] = {}, k2[2] = {};
  float4 xcur = {};

  if (tid < 512) { xcur = *(const float4*)(gxr + stag * 32); stageAi8(Ab0, row, d0, xcur); }
  {
    const char* src = B2 + (size_t)stag * 32768 + tid * 16;
    gll16(src, Bb0 + tid * 16);
    gll16(src + 16384, Bb0 + 16384 + tid * 16);
  }
  if (tid < 512) xcur = *(const float4*)(gxr + (((stag + 1) & 15)) * 32);

#pragma unroll 1
  for (int c = 0; c < 16; ++c) {
    const int p = c & 1;
    char* Bc = p ? Bb1 : Bb0;  char* Bn = p ? Bb0 : Bb1;
    char* Ac = p ? Ab1 : Ab0;  char* An = p ? Ab0 : Ab1;
    __syncthreads();
    if (c < 15) {
      const char* src = B2 + (size_t)(((c + 1 + stag) & 15)) * 32768 + tid * 16;
      gll16(src, Bn + tid * 16);
      gll16(src + 16384, Bn + 16384 + tid * 16);
    }
    float4 xnext = xcur;
    if (tid < 512) {
      if (c < 14) xnext = *(const float4*)(gxr + (((c + 2 + stag) & 15)) * 32);
      if (c < 15) stageAi8(An, row, d0, xcur);
    }

    const int lo16 = lane * 16;
    i32x4 ah = *(const i32x4*)(Ac + mt * 1024 + lo16);
    i32x4 al = *(const i32x4*)(Ac + 2048 + mt * 1024 + lo16);
#pragma unroll
    for (int nn = 0; nn < 2; ++nn) {
      const int nt = ng * 2 + nn;
      i32x4 bh = *(const i32x4*)(Bc + nt * 1024 + lo16);
      i32x4 bl = *(const i32x4*)(Bc + 16384 + nt * 1024 + lo16);
      MFMA_I8(k1[nn], ah, bh);
      MFMA_I8(k2[nn], ah, bl);
      MFMA_I8(k2[nn], al, bh);
    }
    xcur = xnext;
  }

  // epilogue: rowsum * q_sum over wave's 64 cols, fold 8 ng-waves
  const int b = tile >> 6;   // 64 tiles per batch
  const int c0 = (ng * 2 + 0) * 32 + l31, c1 = (ng * 2 + 1) * 32 + l31;
  const float qs0 = q_sum[b * 512 + c0], qs1 = q_sum[b * 512 + c1];
  const float bk0 = bk[c0], bk1 = bk[c1];
  __syncthreads();
#pragma unroll
  for (int r = 0; r < 16; ++r) {
    float p0 = __builtin_fmaf((float)k1[0][r], SC1,
               __builtin_fmaf((float)k2[0][r], SC2, bk0));
    float p1 = __builtin_fmaf((float)k1[1][r], SC1,
               __builtin_fmaf((float)k2[1][r], SC2, bk1));
    float s = ftanh(p0) * qs0 + ftanh(p1) * qs1;
#pragma unroll
    for (int off = 1; off <= 16; off <<= 1) s += __shfl_xor(s, off);
    if (l31 == 0) redk[ng * 64 + mt * 32 + (r & 3) + 8 * (r >> 2) + 4 * hs] = s;
  }
  __syncthreads();
  if (tid < 64) {
    float s = 0.f;
#pragma unroll
    for (int j = 0; j < 8; ++j) s += redk[j * 64 + tid];
    scores[(size_t)tile * 64 + tid] = s;
  }
}

// q_sum[b][e] = sum of the batch's 64 tile partials (64-row tiles)
__global__ void reduce_q(const float* __restrict__ qpart, float* __restrict__ q_sum) {
  int b = blockIdx.x, e = threadIdx.x;
  const float* p = qpart + (size_t)b * 64 * 512 + e;
  float s = 0.f;
#pragma unroll 4
  for (int j = 0; j < 64; ++j) s += p[j * 512];
  q_sum[b * 512 + e] = s;
}

// per-batch masked softmax over scaled scores, times sv
__global__ void softmax_out(const float* __restrict__ scores,
                            const float* __restrict__ sv,
                            const int* __restrict__ lens,
                            float* __restrict__ out) {
  const int b = blockIdx.x, tid = threadIdx.x;   // 256
  const int lane = tid & 63, wid = tid >> 6;
  const int len = lens[b];
  const float scale = 0.04419417382415922f;      // 1/sqrt(512)
  __shared__ float sb[4], sb2[4];

  float sreg[16];
  const float* sc = scores + (size_t)b * 4096;
#pragma unroll
  for (int j = 0; j < 16; ++j) sreg[j] = sc[tid + j * 256] * scale;

  float m = -1e30f;
#pragma unroll
  for (int j = 0; j < 16; ++j)
    if (tid + j * 256 < len) m = fmaxf(m, sreg[j]);
#pragma unroll
  for (int off = 32; off >= 1; off >>= 1) m = fmaxf(m, __shfl_xor(m, off));
  if (lane == 0) sb[wid] = m;
  __syncthreads();
  m = fmaxf(fmaxf(sb[0], sb[1]), fmaxf(sb[2], sb[3]));

  float s = 0.f;
#pragma unroll
  for (int j = 0; j < 16; ++j)
    if (tid + j * 256 < len) s += expf(sreg[j] - m);
#pragma unroll
  for (int off = 32; off >= 1; off >>= 1) s += __shfl_xor(s, off);
  if (lane == 0) sb2[wid] = s;
  __syncthreads();
  const float inv = 1.f / (sb2[0] + sb2[1] + sb2[2] + sb2[3]);

  const float* svb = sv + (size_t)b * 4096;
  float* ob = out + (size_t)b * 4096;
#pragma unroll
  for (int j = 0; j < 16; ++j) {
    int l = tid + j * 256;
    ob[l] = (l < len) ? svb[l] * expf(sreg[j] - m) * inv : 0.0f;
  }
}

extern "C" void kernel_launch(void* const* d_in, const int* in_sizes, int n_in,
                              void* d_out, int out_size, void* d_ws, size_t ws_size,
                              hipStream_t stream) {
  const float* x  = (const float*)d_in[0];
  const float* Wk = (const float*)d_in[1];
  const float* bk = (const float*)d_in[2];
  const float* Wq = (const float*)d_in[3];
  const float* bq = (const float*)d_in[4];
  const float* Wv = (const float*)d_in[5];
  const float* bv = (const float*)d_in[6];
  const int* lens = (const int*)d_in[7];
  float* out = (float*)d_out;

  char* ws = (char*)d_ws;
  char*  B1     = ws;                          // 1 MB   (Q+V W pack)
  char*  B2     = ws + 1048576;                // 512 KB (K W pack)
  float* qpart  = (float*)(ws + 1572864);      // [1024][512] f32 = 2 MB
  float* q_sum  = (float*)(ws + 3670016);      // [16][512] = 32 KB
  float* svbuf  = (float*)(ws + 3702784);      // [65536] = 256 KB
  float* scores = (float*)(ws + 3964928);      // [65536] = 256 KB

  prep_w<<<384, 256, 0, stream>>>(Wq, Wk, Wv, B1, B2);
  pass_q<<<1024, 1024, 77824, stream>>>(x, B1, bq, qpart);
  pass_v<<<1024, 1024, 75776, stream>>>(x, B1, bv, svbuf);
  reduce_q<<<16, 512, 0, stream>>>(qpart, q_sum);
  pass_k<<<1024, 1024, 75776, stream>>>(x, B2, bk, q_sum, scores);
  softmax_out<<<16, 256, 0, stream>>>(scores, svbuf, lens, out);
}